// Round 6
// baseline (142.200 us; speedup 1.0000x reference)
//
#include <hip/hip_runtime.h>

// Causal attention head. B=4, T=4096, C=384, H=16. fp32 in/out.
// Round 12: MEASUREMENT ROUND #2 (budget decomposition). Three structural
// flash changes (R7 VALU trim, R8 balance, R11 reg-prefetch) all neutral at
// ~102.6us; latency arithmetic says flash's serial chain is only ~2.4us yet
// it measures ~17us (R9); and ~34us of the budget (wconv+qkv+merge+gaps) has
// never been measured -- the 43us harness fills hide every kernel <43us from
// the top-5. This round: wconv x4, qkv x4, flash x1 (unchanged v8), merge x4
// (all idempotent). (total - 102.6)/3 = wconv + qkv + merge + 3*gap.
// Routing: sum>=15us -> fuse/optimize those kernels; sum<=8us -> residual is
// launch machinery -> persistent-kernel fusion.
// Fixed harness floor ~52us (256MB ws re-poison 44us + restores) on top.

constexpr int B_DIM = 4;
constexpr int T_SEQ = 4096;
constexpr int C_DIM = 384;
constexpr int H_DIM = 16;
constexpr int NROW  = B_DIM * T_SEQ; // 16384
constexpr int NSLOT = 16;

typedef __bf16 bf16x8 __attribute__((ext_vector_type(8)));
typedef float  f32x4  __attribute__((ext_vector_type(4)));

__device__ __forceinline__ unsigned short f2bf(float f) {
  unsigned int u = __builtin_bit_cast(unsigned int, f);
  u += 0x7fffu + ((u >> 16) & 1u);   // RNE (finite inputs)
  return (unsigned short)(u >> 16);
}
__device__ __forceinline__ bf16x8 as_bf16x8(uint4 u) {
  return __builtin_bit_cast(bf16x8, u);
}
__device__ __forceinline__ unsigned cvt_pk_bf16(float lo, float hi) {
  unsigned r;
  asm("v_cvt_pk_bf16_f32 %0, %1, %2" : "=v"(r) : "v"(lo), "v"(hi));
  return r;
}

// ---------------------------------------------------------------------------
// Kernel 0: W -> WT bf16, layout [m][n=16][k=384]. 18432 elements.
// ---------------------------------------------------------------------------
__global__ __launch_bounds__(256) void wconv(
    const float* __restrict__ Wk, const float* __restrict__ Wq,
    const float* __restrict__ Wv, unsigned short* __restrict__ WT) {
  const int i = blockIdx.x * 256 + threadIdx.x;   // grid 72*256 = 18432
  const int m = i / 6144;
  const int r = i - m * 6144;
  const int n = r / 384;
  const int k = r - n * 384;
  const float* __restrict__ W = (m == 0) ? Wk : (m == 1) ? Wq : Wv;
  WT[i] = f2bf(W[k * 16 + n]);
}

// ---------------------------------------------------------------------------
// Kernel 1: QKV projection via MFMA, 2-way K-split (unchanged).
// ---------------------------------------------------------------------------
__global__ __launch_bounds__(128) void qkv_mfma(
    const float* __restrict__ x, const unsigned short* __restrict__ WT,
    unsigned short* __restrict__ Kb,   // [NROW][16]
    unsigned short* __restrict__ Qb,   // [NROW][32] scaled + zero-padded
    unsigned short* __restrict__ VTb)  // [B][16][T]
{
  const int tid  = threadIdx.x;
  const int w    = tid >> 6;           // 0..1
  const int lane = tid & 63;
  const int quad = lane >> 4;
  const int col  = lane & 15;
  const int r0   = blockIdx.x << 4;
  const int kb   = w * 6;              // this wave's kk base

  __shared__ float mrg[12][64];

  const float4* __restrict__ xp =
      reinterpret_cast<const float4*>(x + (size_t)(r0 + col) * C_DIM) + quad * 2;
  float4 araw[12];
#pragma unroll
  for (int kk = 0; kk < 6; ++kk) {
    araw[2 * kk]     = xp[(kb + kk) * 8];
    araw[2 * kk + 1] = xp[(kb + kk) * 8 + 1];
  }

  const uint4* __restrict__ bk = reinterpret_cast<const uint4*>(
      WT + (size_t)col * 384 + quad * 8);
  const uint4* __restrict__ bq = bk + 768;    // +6144 shorts
  const uint4* __restrict__ bv = bk + 1536;   // +12288 shorts

  f32x4 ck = {0.f, 0.f, 0.f, 0.f};
  f32x4 cq = {0.f, 0.f, 0.f, 0.f};
  f32x4 cv = {0.f, 0.f, 0.f, 0.f};
#pragma unroll
  for (int kk = 0; kk < 6; ++kk) {
    uint4 pk;
    const float4 a0 = araw[2 * kk], a1 = araw[2 * kk + 1];
    pk.x = cvt_pk_bf16(a0.x, a0.y);
    pk.y = cvt_pk_bf16(a0.z, a0.w);
    pk.z = cvt_pk_bf16(a1.x, a1.y);
    pk.w = cvt_pk_bf16(a1.z, a1.w);
    const bf16x8 av = as_bf16x8(pk);
    ck = __builtin_amdgcn_mfma_f32_16x16x32_bf16(av, as_bf16x8(bk[(kb + kk) * 4]), ck, 0, 0, 0);
    cq = __builtin_amdgcn_mfma_f32_16x16x32_bf16(av, as_bf16x8(bq[(kb + kk) * 4]), cq, 0, 0, 0);
    cv = __builtin_amdgcn_mfma_f32_16x16x32_bf16(av, as_bf16x8(bv[(kb + kk) * 4]), cv, 0, 0, 0);
  }

  if (w == 1) {
#pragma unroll
    for (int r = 0; r < 4; ++r) {
      mrg[r][lane]     = ck[r];
      mrg[4 + r][lane] = cq[r];
      mrg[8 + r][lane] = cv[r];
    }
  }
  __syncthreads();
  if (w == 0) {
    const float SC = 0.25f * 1.44269504088896341f;  // softmax scale * log2(e)
#pragma unroll
    for (int r = 0; r < 4; ++r) {
      const float vk = ck[r] + mrg[r][lane];
      const float vq = cq[r] + mrg[4 + r][lane];
      const float vv = cv[r] + mrg[8 + r][lane];
      const int row = r0 + quad * 4 + r;
      Kb[row * 16 + col]      = f2bf(vk);
      Qb[row * 32 + col]      = f2bf(vq * SC);
      Qb[row * 32 + 16 + col] = 0;
      const int bb = row >> 12, t = row & 4095;
      VTb[(((size_t)(bb * 16 + col)) << 12) + t] = f2bf(vv);
    }
  }
}

// ---------------------------------------------------------------------------
// Kernel 2: bf16 MFMA flash attention, antidiagonal-paired, reg-prefetched.
// (unchanged from R11)
// ---------------------------------------------------------------------------
__global__ __launch_bounds__(256) void flash_v8(
    const unsigned short* __restrict__ Qb,
    const unsigned short* __restrict__ Kb,
    const unsigned short* __restrict__ VTb,
    float* __restrict__ PO, float* __restrict__ PL)
{
  const int tid  = threadIdx.x;
  const int w    = tid >> 6;
  const int lane = tid & 63;
  const int quad = lane >> 4;
  const int col  = lane & 15;
  const int p    = blockIdx.x >> 4;          // 0..127
  const int b    = (blockIdx.x >> 2) & 3;
  const int j    = blockIdx.x & 3;
  const int slot = (j << 2) | w;             // 0..15
  const int qtA  = 255 - p;
  const int qtB  = p;
  const int nchA = (qtA + 4) >> 2;           // 33..64; nchA + nchB == 65

  __shared__ __attribute__((aligned(16))) unsigned short Pl[4][16 * 72];
  unsigned short* const P = Pl[w];

  const unsigned short* Kbase = Kb + ((size_t)(b * T_SEQ) << 4);
  const unsigned short* Vbase = VTb + (((size_t)(b * 16 + col)) << 12);
  const int poff = col * 72 + quad * 4;      // P store offset (shorts)

  f32x4 o = {0.f, 0.f, 0.f, 0.f};

  // Q fragments for both phases up front (kills the boundary stall).
  const uint4* qpA = reinterpret_cast<const uint4*>(
      Qb + (((size_t)(b * T_SEQ + (qtA << 4) + col)) << 5) + quad * 8);
  const uint4* qpB = reinterpret_cast<const uint4*>(
      Qb + (((size_t)(b * T_SEQ + (qtB << 4) + col)) << 5) + quad * 8);
  const bf16x8 qaA = as_bf16x8(qpA[0]);
  const bf16x8 qaB = as_bf16x8(qpB[0]);

  auto loadK = [&](int c, uint4* k4) {
    const int kt0 = c << 2;
#pragma unroll
    for (int t = 0; t < 4; ++t)
      k4[t] = *reinterpret_cast<const uint4*>(
          Kbase + (((size_t)((kt0 + t) * 16 + col)) << 4) + quad * 8);
  };
  auto loadV = [&](int c, uint4* v2) {
    v2[0] = *reinterpret_cast<const uint4*>(Vbase + c * 64 + quad * 8);
    v2[1] = *reinterpret_cast<const uint4*>(Vbase + c * 64 + 32 + quad * 8);
  };

  auto computeP = [&](int qt, bf16x8 qa, int c, const uint4* k4, float& lref) {
    const int kt0 = c << 2;
    float lsum = 0.f;
#pragma unroll
    for (int t = 0; t < 4; ++t) {
      const int kt = kt0 + t;
      f32x4 sf;
      if (kt <= qt) {
        f32x4 z = {0.f, 0.f, 0.f, 0.f};
        // swapped: A = K tile (rows=keys), B = Q tile (cols=q). C[key][q]:
        //   q = col, key = t*16 + quad*4 + r (consecutive in r)
        sf = __builtin_amdgcn_mfma_f32_16x16x32_bf16(as_bf16x8(k4[t]), qa, z, 0, 0, 0);
        if (kt == qt) {
#pragma unroll
          for (int r = 0; r < 4; ++r)
            if (quad * 4 + r > col) sf[r] = -1e30f;   // key > q
        }
      } else {
#pragma unroll
        for (int r = 0; r < 4; ++r) sf[r] = -1e30f;
      }
      const float p0 = __builtin_amdgcn_exp2f(sf[0]);  // -1e30 -> 0
      const float p1 = __builtin_amdgcn_exp2f(sf[1]);
      const float p2 = __builtin_amdgcn_exp2f(sf[2]);
      const float p3 = __builtin_amdgcn_exp2f(sf[3]);
      lsum += (p0 + p1) + (p2 + p3);
      uint2 pr;
      pr.x = cvt_pk_bf16(p0, p1);   // RNE, same as f2bf
      pr.y = cvt_pk_bf16(p2, p3);
      *reinterpret_cast<uint2*>(P + poff + t * 16) = pr;  // ds_write_b64
    }
    lref += lsum;
  };

  // P reads use uint2 (same type as writes) so the compiler must preserve
  // read-before-overwrite order vs computeP's stores into the same buffer.
  auto doPV = [&](const uint4* v2) {
    const uint2* pp = reinterpret_cast<const uint2*>(P + col * 72);
    const uint2 a0 = pp[quad * 2],     a1 = pp[quad * 2 + 1];
    const uint2 b0 = pp[8 + quad * 2], b1 = pp[8 + quad * 2 + 1];
    const uint4 p0 = {a0.x, a0.y, a1.x, a1.y};
    const uint4 p1 = {b0.x, b0.y, b1.x, b1.y};
    o = __builtin_amdgcn_mfma_f32_16x16x32_bf16(as_bf16x8(p0), as_bf16x8(v2[0]), o, 0, 0, 0);
    o = __builtin_amdgcn_mfma_f32_16x16x32_bf16(as_bf16x8(p1), as_bf16x8(v2[1]), o, 0, 0, 0);
  };

  auto writePartial = [&](int qt, float lsum) {
    float l = lsum;
    l += __shfl_xor(l, 16);
    l += __shfl_xor(l, 32);
    const size_t rowbase = (size_t)b * T_SEQ + ((size_t)qt << 4);
    float* pO = PO + ((size_t)slot * NROW + rowbase) * 16;
#pragma unroll
    for (int r = 0; r < 4; ++r)
      pO[(quad * 4 + r) * 16 + col] = o[r];
    if (quad == 0) PL[(size_t)slot * NROW + rowbase + col] = l;
  };

  float lA = 0.f, lB = 0.f;
  uint4 k4[4], vcur[2], vnxt[2];

  // first chunk: g0 = slot (always phase A since slot < 16 < 33 <= nchA)
  int g = slot;
  loadK(g, k4);
  loadV(g, vcur);
  computeP(qtA, qaA, g, k4, lA);

  int prevg = g;
  g += 16;
  while (g < 65) {
    const int c = (g < nchA) ? g : g - nchA;
    loadK(c, k4);                       // issue next chunk's K (k4 dead now)
    loadV(c, vnxt);                     // issue next chunk's V
    doPV(vcur);                         // PV of prevg (V regs already arrived)
    asm volatile("" ::: "memory");      // P reads stay above P overwrites
    if (prevg < nchA && g >= nchA) {    // phase boundary: flush A partial
      writePartial(qtA, lA);
      o = (f32x4){0.f, 0.f, 0.f, 0.f};
    }
    if (g < nchA) computeP(qtA, qaA, c, k4, lA);
    else          computeP(qtB, qaB, c, k4, lB);
    vcur[0] = vnxt[0];
    vcur[1] = vnxt[1];
    prevg = g;
    g += 16;
  }
  doPV(vcur);                           // PV of the last chunk
  if (prevg < nchA) {                   // wave never reached phase B
    writePartial(qtA, lA);
    o = (f32x4){0.f, 0.f, 0.f, 0.f};
    writePartial(qtB, 0.f);             // zero partial for B
  } else {
    writePartial(qtB, lB);
  }
}

// ---------------------------------------------------------------------------
// Kernel 3: merge 16 partial slots: out = sum(O) / sum(l).
// ---------------------------------------------------------------------------
__global__ __launch_bounds__(256) void flash_merge(
    const float* __restrict__ PO, const float* __restrict__ PL,
    float* __restrict__ out)
{
  const int i   = blockIdx.x * 256 + threadIdx.x;   // grid 1024*256 = 262144
  const int row = i >> 4;
  float O = 0.f, L = 0.f;
#pragma unroll
  for (int s = 0; s < NSLOT; ++s) {
    O += PO[((size_t)s * NROW) * 16 + i];
    L += PL[(size_t)s * NROW + row];
  }
  out[i] = O / L;
}

extern "C" void kernel_launch(void* const* d_in, const int* in_sizes, int n_in,
                              void* d_out, int out_size, void* d_ws, size_t ws_size,
                              hipStream_t stream) {
  const float* x  = (const float*)d_in[0];
  const float* Wk = (const float*)d_in[1];
  const float* Wq = (const float*)d_in[2];
  const float* Wv = (const float*)d_in[3];
  float* outp = (float*)d_out;

  // ws: Qb [NROW*32]sh | Kb [NROW*16]sh | 64 slack | VTb [NROW*16]sh |
  //     WT [18432]sh | PO [16*NROW*16]f32 | PL [16*NROW]f32   (~20 MB total)
  unsigned short* Qb  = (unsigned short*)d_ws;
  unsigned short* Kb  = Qb + (size_t)NROW * 32;
  unsigned short* VTb = Kb + (size_t)NROW * 16 + 64;
  unsigned short* WT  = VTb + (size_t)NROW * 16;
  float* PO = (float*)(WT + 18432);
  float* PL = PO + (size_t)NSLOT * NROW * 16;

  // MEASUREMENT: wconv/qkv/merge x4 (all idempotent), flash x1 unchanged.
  // (total - 102.6)/3 = wconv + qkv + merge + 3*launch-gap.
  wconv<<<72, 256, 0, stream>>>(Wk, Wq, Wv, WT);
  wconv<<<72, 256, 0, stream>>>(Wk, Wq, Wv, WT);
  wconv<<<72, 256, 0, stream>>>(Wk, Wq, Wv, WT);
  wconv<<<72, 256, 0, stream>>>(Wk, Wq, Wv, WT);
  qkv_mfma<<<1024, 128, 0, stream>>>(x, WT, Kb, Qb, VTb);
  qkv_mfma<<<1024, 128, 0, stream>>>(x, WT, Kb, Qb, VTb);
  qkv_mfma<<<1024, 128, 0, stream>>>(x, WT, Kb, Qb, VTb);
  qkv_mfma<<<1024, 128, 0, stream>>>(x, WT, Kb, Qb, VTb);
  flash_v8<<<2048, 256, 0, stream>>>(Qb, Kb, VTb, PO, PL);
  flash_merge<<<1024, 256, 0, stream>>>(PO, PL, outp);
  flash_merge<<<1024, 256, 0, stream>>>(PO, PL, outp);
  flash_merge<<<1024, 256, 0, stream>>>(PO, PL, outp);
  flash_merge<<<1024, 256, 0, stream>>>(PO, PL, outp);
}

// Round 7
// 94.821 us; speedup vs baseline: 1.4997x; 1.4997x over previous
//
#include <hip/hip_runtime.h>

// Causal attention head. B=4, T=4096, C=384, H=16. fp32 in/out.
// Round 13: traffic/structure attack from the R12 budget: controllable
// ~30us = flash+gap 16.9 | qkv ~4 | merge ~2.5 | wconv ~1 | gaps ~6.
// Flash is traffic-bound (three chain-level edits all neutral; ~200MB L2
// reads + 35MB PO/PL round-trip). This round removes the merge kernel and
// the PO/PL global partials entirely: one block per (pair,b) -- grid 512 x
// 8 waves. Wave w walks chunks g=w,w+8,...<65 (antidiagonal pair => uniform
// 65 chunks). Phase A->B + reg-prefetch + single P buffer carried from v8.
// Partials -> LDS (8x2x(1KB O + 64B l)), one __syncthreads, 512 threads
// reduce and write out directly. Launches 4->3. LDS 36KB -> 4 blocks/CU.
// Fixed harness floor (256MB ws re-poison ~44us + restores) on top.

constexpr int B_DIM = 4;
constexpr int T_SEQ = 4096;
constexpr int C_DIM = 384;
constexpr int H_DIM = 16;
constexpr int NROW  = B_DIM * T_SEQ; // 16384

typedef __bf16 bf16x8 __attribute__((ext_vector_type(8)));
typedef float  f32x4  __attribute__((ext_vector_type(4)));

__device__ __forceinline__ unsigned short f2bf(float f) {
  unsigned int u = __builtin_bit_cast(unsigned int, f);
  u += 0x7fffu + ((u >> 16) & 1u);   // RNE (finite inputs)
  return (unsigned short)(u >> 16);
}
__device__ __forceinline__ bf16x8 as_bf16x8(uint4 u) {
  return __builtin_bit_cast(bf16x8, u);
}
__device__ __forceinline__ unsigned cvt_pk_bf16(float lo, float hi) {
  unsigned r;
  asm("v_cvt_pk_bf16_f32 %0, %1, %2" : "=v"(r) : "v"(lo), "v"(hi));
  return r;
}

// ---------------------------------------------------------------------------
// Kernel 0: W -> WT bf16, layout [m][n=16][k=384]. 18432 elements.
// ---------------------------------------------------------------------------
__global__ __launch_bounds__(256) void wconv(
    const float* __restrict__ Wk, const float* __restrict__ Wq,
    const float* __restrict__ Wv, unsigned short* __restrict__ WT) {
  const int i = blockIdx.x * 256 + threadIdx.x;   // grid 72*256 = 18432
  const int m = i / 6144;
  const int r = i - m * 6144;
  const int n = r / 384;
  const int k = r - n * 384;
  const float* __restrict__ W = (m == 0) ? Wk : (m == 1) ? Wq : Wv;
  WT[i] = f2bf(W[k * 16 + n]);
}

// ---------------------------------------------------------------------------
// Kernel 1: QKV projection via MFMA, 2-way K-split (unchanged).
// ---------------------------------------------------------------------------
__global__ __launch_bounds__(128) void qkv_mfma(
    const float* __restrict__ x, const unsigned short* __restrict__ WT,
    unsigned short* __restrict__ Kb,   // [NROW][16]
    unsigned short* __restrict__ Qb,   // [NROW][32] scaled + zero-padded
    unsigned short* __restrict__ VTb)  // [B][16][T]
{
  const int tid  = threadIdx.x;
  const int w    = tid >> 6;           // 0..1
  const int lane = tid & 63;
  const int quad = lane >> 4;
  const int col  = lane & 15;
  const int r0   = blockIdx.x << 4;
  const int kb   = w * 6;              // this wave's kk base

  __shared__ float mrg[12][64];

  const float4* __restrict__ xp =
      reinterpret_cast<const float4*>(x + (size_t)(r0 + col) * C_DIM) + quad * 2;
  float4 araw[12];
#pragma unroll
  for (int kk = 0; kk < 6; ++kk) {
    araw[2 * kk]     = xp[(kb + kk) * 8];
    araw[2 * kk + 1] = xp[(kb + kk) * 8 + 1];
  }

  const uint4* __restrict__ bk = reinterpret_cast<const uint4*>(
      WT + (size_t)col * 384 + quad * 8);
  const uint4* __restrict__ bq = bk + 768;    // +6144 shorts
  const uint4* __restrict__ bv = bk + 1536;   // +12288 shorts

  f32x4 ck = {0.f, 0.f, 0.f, 0.f};
  f32x4 cq = {0.f, 0.f, 0.f, 0.f};
  f32x4 cv = {0.f, 0.f, 0.f, 0.f};
#pragma unroll
  for (int kk = 0; kk < 6; ++kk) {
    uint4 pk;
    const float4 a0 = araw[2 * kk], a1 = araw[2 * kk + 1];
    pk.x = cvt_pk_bf16(a0.x, a0.y);
    pk.y = cvt_pk_bf16(a0.z, a0.w);
    pk.z = cvt_pk_bf16(a1.x, a1.y);
    pk.w = cvt_pk_bf16(a1.z, a1.w);
    const bf16x8 av = as_bf16x8(pk);
    ck = __builtin_amdgcn_mfma_f32_16x16x32_bf16(av, as_bf16x8(bk[(kb + kk) * 4]), ck, 0, 0, 0);
    cq = __builtin_amdgcn_mfma_f32_16x16x32_bf16(av, as_bf16x8(bq[(kb + kk) * 4]), cq, 0, 0, 0);
    cv = __builtin_amdgcn_mfma_f32_16x16x32_bf16(av, as_bf16x8(bv[(kb + kk) * 4]), cv, 0, 0, 0);
  }

  if (w == 1) {
#pragma unroll
    for (int r = 0; r < 4; ++r) {
      mrg[r][lane]     = ck[r];
      mrg[4 + r][lane] = cq[r];
      mrg[8 + r][lane] = cv[r];
    }
  }
  __syncthreads();
  if (w == 0) {
    const float SC = 0.25f * 1.44269504088896341f;  // softmax scale * log2(e)
#pragma unroll
    for (int r = 0; r < 4; ++r) {
      const float vk = ck[r] + mrg[r][lane];
      const float vq = cq[r] + mrg[4 + r][lane];
      const float vv = cv[r] + mrg[8 + r][lane];
      const int row = r0 + quad * 4 + r;
      Kb[row * 16 + col]      = f2bf(vk);
      Qb[row * 32 + col]      = f2bf(vq * SC);
      Qb[row * 32 + 16 + col] = 0;
      const int bb = row >> 12, t = row & 4095;
      VTb[(((size_t)(bb * 16 + col)) << 12) + t] = f2bf(vv);
    }
  }
}

// ---------------------------------------------------------------------------
// Kernel 2: bf16 MFMA flash attention, antidiagonal-paired, reg-prefetched,
// BLOCK-LOCAL merge. grid 512: blk = p*4 + b. 8 waves; wave w walks chunks
// g = w, w+8, ... < 65 across pair (qtA=255-p, qtB=p). Partials to LDS,
// one barrier, 512-thread reduce, direct out write. No PO/PL, no merge krn.
// ---------------------------------------------------------------------------
__global__ __launch_bounds__(512) void flash_v9(
    const unsigned short* __restrict__ Qb,
    const unsigned short* __restrict__ Kb,
    const unsigned short* __restrict__ VTb,
    float* __restrict__ out)
{
  const int tid  = threadIdx.x;
  const int w    = tid >> 6;                 // 0..7
  const int lane = tid & 63;
  const int quad = lane >> 4;
  const int col  = lane & 15;
  const int p    = blockIdx.x >> 2;          // 0..127
  const int b    = blockIdx.x & 3;
  const int qtA  = 255 - p;
  const int qtB  = p;
  const int nchA = (qtA + 4) >> 2;           // 33..64; nchA + nchB == 65

  __shared__ __attribute__((aligned(16))) unsigned short Pl[8][16 * 72]; // 18.4KB
  __shared__ float mO[8][2][256];                                        // 16KB
  __shared__ float mL[8][2][16];                                         // 1KB
  unsigned short* const P = Pl[w];

  const unsigned short* Kbase = Kb + ((size_t)(b * T_SEQ) << 4);
  const unsigned short* Vbase = VTb + (((size_t)(b * 16 + col)) << 12);
  const int poff = col * 72 + quad * 4;      // P store offset (shorts)

  f32x4 o = {0.f, 0.f, 0.f, 0.f};

  // Q fragments for both phases up front.
  const uint4* qpA = reinterpret_cast<const uint4*>(
      Qb + (((size_t)(b * T_SEQ + (qtA << 4) + col)) << 5) + quad * 8);
  const uint4* qpB = reinterpret_cast<const uint4*>(
      Qb + (((size_t)(b * T_SEQ + (qtB << 4) + col)) << 5) + quad * 8);
  const bf16x8 qaA = as_bf16x8(qpA[0]);
  const bf16x8 qaB = as_bf16x8(qpB[0]);

  auto loadK = [&](int c, uint4* k4) {
    const int kt0 = c << 2;
#pragma unroll
    for (int t = 0; t < 4; ++t)
      k4[t] = *reinterpret_cast<const uint4*>(
          Kbase + (((size_t)((kt0 + t) * 16 + col)) << 4) + quad * 8);
  };
  auto loadV = [&](int c, uint4* v2) {
    v2[0] = *reinterpret_cast<const uint4*>(Vbase + c * 64 + quad * 8);
    v2[1] = *reinterpret_cast<const uint4*>(Vbase + c * 64 + 32 + quad * 8);
  };

  auto computeP = [&](int qt, bf16x8 qa, int c, const uint4* k4, float& lref) {
    const int kt0 = c << 2;
    float lsum = 0.f;
#pragma unroll
    for (int t = 0; t < 4; ++t) {
      const int kt = kt0 + t;
      f32x4 sf;
      if (kt <= qt) {
        f32x4 z = {0.f, 0.f, 0.f, 0.f};
        // swapped: A = K tile (rows=keys), B = Q tile (cols=q). C[key][q]:
        //   q = col, key = t*16 + quad*4 + r (consecutive in r)
        sf = __builtin_amdgcn_mfma_f32_16x16x32_bf16(as_bf16x8(k4[t]), qa, z, 0, 0, 0);
        if (kt == qt) {
#pragma unroll
          for (int r = 0; r < 4; ++r)
            if (quad * 4 + r > col) sf[r] = -1e30f;   // key > q
        }
      } else {
#pragma unroll
        for (int r = 0; r < 4; ++r) sf[r] = -1e30f;
      }
      const float p0 = __builtin_amdgcn_exp2f(sf[0]);  // -1e30 -> 0
      const float p1 = __builtin_amdgcn_exp2f(sf[1]);
      const float p2 = __builtin_amdgcn_exp2f(sf[2]);
      const float p3 = __builtin_amdgcn_exp2f(sf[3]);
      lsum += (p0 + p1) + (p2 + p3);
      uint2 pr;
      pr.x = cvt_pk_bf16(p0, p1);   // RNE, same as f2bf
      pr.y = cvt_pk_bf16(p2, p3);
      *reinterpret_cast<uint2*>(P + poff + t * 16) = pr;  // ds_write_b64
    }
    lref += lsum;
  };

  // P reads typed uint2 (same as writes) -> compiler preserves
  // read-before-overwrite order vs computeP's stores into the same buffer.
  auto doPV = [&](const uint4* v2) {
    const uint2* pp = reinterpret_cast<const uint2*>(P + col * 72);
    const uint2 a0 = pp[quad * 2],     a1 = pp[quad * 2 + 1];
    const uint2 b0 = pp[8 + quad * 2], b1 = pp[8 + quad * 2 + 1];
    const uint4 p0 = {a0.x, a0.y, a1.x, a1.y};
    const uint4 p1 = {b0.x, b0.y, b1.x, b1.y};
    o = __builtin_amdgcn_mfma_f32_16x16x32_bf16(as_bf16x8(p0), as_bf16x8(v2[0]), o, 0, 0, 0);
    o = __builtin_amdgcn_mfma_f32_16x16x32_bf16(as_bf16x8(p1), as_bf16x8(v2[1]), o, 0, 0, 0);
  };

  auto writePartial = [&](int ph, float lsum) {   // to LDS merge slabs
    float l = lsum;
    l += __shfl_xor(l, 16);
    l += __shfl_xor(l, 32);
#pragma unroll
    for (int r = 0; r < 4; ++r)
      mO[w][ph][(quad * 4 + r) * 16 + col] = o[r];
    if (quad == 0) mL[w][ph][col] = l;
  };

  float lA = 0.f, lB = 0.f;
  uint4 k4[4], vcur[2], vnxt[2];

  // first chunk: g0 = w (always phase A since w < 8 < 33 <= nchA)
  int g = w;
  loadK(g, k4);
  loadV(g, vcur);
  computeP(qtA, qaA, g, k4, lA);

  int prevg = g;
  g += 8;
  while (g < 65) {
    const int c = (g < nchA) ? g : g - nchA;
    loadK(c, k4);                       // issue next chunk's K (k4 dead now)
    loadV(c, vnxt);                     // issue next chunk's V
    doPV(vcur);                         // PV of prevg (V regs arrived)
    asm volatile("" ::: "memory");      // P reads stay above P overwrites
    if (prevg < nchA && g >= nchA) {    // phase boundary: flush A partial
      writePartial(0, lA);
      o = (f32x4){0.f, 0.f, 0.f, 0.f};
    }
    if (g < nchA) computeP(qtA, qaA, c, k4, lA);
    else          computeP(qtB, qaB, c, k4, lB);
    vcur[0] = vnxt[0];
    vcur[1] = vnxt[1];
    prevg = g;
    g += 8;
  }
  doPV(vcur);                           // PV of the last chunk
  if (prevg < nchA) {                   // wave never reached phase B
    writePartial(0, lA);
    o = (f32x4){0.f, 0.f, 0.f, 0.f};
    writePartial(1, 0.f);               // zero partial for B
  } else {
    writePartial(1, lB);
  }

  __syncthreads();

  // ---- block-local merge: 512 threads, tid>>8 = phase, tid&255 = elem ----
  {
    const int ph = tid >> 8;            // 0 -> qtA, 1 -> qtB
    const int i  = tid & 255;           // (row<<4)|col within the 16x16 tile
    float O = 0.f, L = 0.f;
#pragma unroll
    for (int ww = 0; ww < 8; ++ww) {
      O += mO[ww][ph][i];
      L += mL[ww][ph][i >> 4];
    }
    const int qt = ph ? qtB : qtA;
    out[(size_t)(b * T_SEQ + (qt << 4)) * 16 + i] = O / L;
  }
}

extern "C" void kernel_launch(void* const* d_in, const int* in_sizes, int n_in,
                              void* d_out, int out_size, void* d_ws, size_t ws_size,
                              hipStream_t stream) {
  const float* x  = (const float*)d_in[0];
  const float* Wk = (const float*)d_in[1];
  const float* Wq = (const float*)d_in[2];
  const float* Wv = (const float*)d_in[3];
  float* outp = (float*)d_out;

  // ws: Qb [NROW*32]sh | Kb [NROW*16]sh | 64 slack | VTb [NROW*16]sh |
  //     WT [18432]sh   (~1.6 MB total; PO/PL eliminated)
  unsigned short* Qb  = (unsigned short*)d_ws;
  unsigned short* Kb  = Qb + (size_t)NROW * 32;
  unsigned short* VTb = Kb + (size_t)NROW * 16 + 64;
  unsigned short* WT  = VTb + (size_t)NROW * 16;

  wconv<<<72, 256, 0, stream>>>(Wk, Wq, Wv, WT);
  qkv_mfma<<<1024, 128, 0, stream>>>(x, WT, Kb, Qb, VTb);
  flash_v9<<<512, 512, 0, stream>>>(Qb, Kb, VTb, outp);
}